// Round 9
// baseline (51.432 us; speedup 1.0000x reference)
//
#include <hip/hip_runtime.h>
#include <math.h>

// GCDD fused v9: zero-LDS register-pipeline sweep, rotation-3 prefetch +
// row-factorized Sobel + redundant-mask removal.
// out = u + div( phi(G)*ux, phi(G)*uy ); 3x3 Sobel cross-correlations with zero
// padding at EVERY conv stage (intermediates forced to 0 outside the domain).
//
// R8 lesson: depth-4 rotation forced a 12x unroll (~28KB loop -> I$ thrash,
// +48 VGPR). v9 keeps rotation 3 / unroll 3 and instead prefetches into a
// dedicated pend[12] register row consumed at the top of the next iteration
// (load->use distance ~= one full iteration of compute).
//
// Row factorization: per u row store Du[c]=u[c+3]-u[c+1], Su[c]=u[c+1]+2u[c+2]
// +u[c+3] (computed once from pend). Then ux = Du(t)+2Du(m)+Du(b) and
// uy = Su(b)-Su(t): each Du/Su reused by up to 3 ux rows.
// PQ masks removed: ux/uy are already zeroed at invalid cols, phi finite
// (den>=1), so P=phi*ux, Q=phi*uy are automatically 0 outside the domain.
//
// Pipeline at iter T (band-row k <-> abs gy = gy0 + k - 3):
//   C(T):  consume pend (u row T)   -> Du/Su[T%3], ucen[T%3]
//   L'(T): load u band-row T+1      -> pend        (abs gy0+T-2)
//   UX(T): ux/uy band-row T-1       -> xw/yw[(T-1)%3=S2]
//   PQ(T): P,Q band-row T-2 -> pre-reduced dP/eQ[(T-2)%3=S1]
//   OUT(T): out band-row T-3 = u + (dP[r-1]+2dP[r]+dP[r+1]) + (eQ[r+1]-eQ[r-1])
// Block: 256 threads = 2 bands x 128 strips (4 cols each). Grid y = H/(2*HB).

#define HB   16
#define NROW (HB + 6)   // 22 active pipeline iterations (loop padded to 24)
#define NT   256

typedef float f4v __attribute__((ext_vector_type(4)));

// Slots: S0 = T%3, S1 = (T+1)%3, S2 = (T+2)%3.
//   Du/Su/ucen[S0] <- row T;  rows T-2,T-1 in S1,S2.
//   xw/yw write S2 (row T-1); PQ reads S0,S1,S2 (rows T-3,T-2,T-1), writes
//   dP/eQ[S1] (row T-2); OUT reads dP/eQ S2,S0,S1 (rows T-4,T-3,T-2) and
//   residual ucen[S0] (row T-3, saved before C(T) overwrites).
#define STEP(TT, S0, S1, S2) do {                                              \
    const int Tt = (TT);                                                       \
    const float ur0 = ucen[S0][0], ur1 = ucen[S0][1],                          \
                ur2 = ucen[S0][2], ur3 = ucen[S0][3];                          \
    if (Tt < NROW) {                                                           \
        /* ---- C(Tt): consume pend (u row Tt) -> Du/Su/ucen[S0] ---- */       \
        float* du = Du[S0]; float* su = Su[S0];                                \
        _Pragma("unroll") for (int c = 0; c < 8; ++c) {                        \
            du[c] = pend[c+3] - pend[c+1];                                     \
            su[c] = pend[c+1] + 2.f*pend[c+2] + pend[c+3];                     \
        }                                                                      \
        ucen[S0][0] = pend[4]; ucen[S0][1] = pend[5];                          \
        ucen[S0][2] = pend[6]; ucen[S0][3] = pend[7];                          \
    }                                                                          \
    if (Tt + 1 < NROW) {                                                       \
        /* ---- L'(Tt): load u band-row Tt+1 -> pend (abs gy=gy0+Tt-2) ---- */ \
        const int gy = gy0 + Tt - 2;                                           \
        if ((unsigned)gy < (unsigned)H) {                                      \
            const float* row = uc + (long)gy * W;                              \
            const float4 va = *(const float4*)(row + ca);                      \
            const float4 vb = *(const float4*)(row + c0);                      \
            const float4 vc = *(const float4*)(row + cc);                      \
            pend[0] = inb0  ? va.x : 0.f;  pend[1]  = inb1  ? va.y : 0.f;      \
            pend[2] = inb2  ? va.z : 0.f;  pend[3]  = inb3  ? va.w : 0.f;      \
            pend[4] = vb.x;                pend[5]  = vb.y;                    \
            pend[6] = vb.z;                pend[7]  = vb.w;                    \
            pend[8] = inb8  ? vc.x : 0.f;  pend[9]  = inb9  ? vc.y : 0.f;      \
            pend[10] = inb10 ? vc.z : 0.f; pend[11] = inb11 ? vc.w : 0.f;      \
        } else {                                                               \
            _Pragma("unroll") for (int i = 0; i < 12; ++i) pend[i] = 0.f;      \
        }                                                                      \
    }                                                                          \
    if (Tt >= 2 && Tt < NROW) {                                                \
        /* ---- UX(Tt): ux/uy band-row Tt-1 (abs gy=gy0+Tt-4) -> slot S2 ---- */ \
        float* xr = xw[S2]; float* yr = yw[S2];                                \
        const int gy = gy0 + Tt - 4;                                           \
        if ((unsigned)gy < (unsigned)H) {                                      \
            /* u rows Tt-2 (S1), Tt-1 (S2), Tt (S0) */                         \
            _Pragma("unroll") for (int c = 0; c < 8; ++c) {                    \
                const float x = Du[S1][c] + 2.f*Du[S2][c] + Du[S0][c];         \
                const float y = Su[S0][c] - Su[S1][c];                         \
                xr[c] = mU[c+2] ? x : 0.f;                                     \
                yr[c] = mU[c+2] ? y : 0.f;                                     \
            }                                                                  \
        } else {                                                               \
            _Pragma("unroll") for (int c = 0; c < 8; ++c) { xr[c]=0.f; yr[c]=0.f; } \
        }                                                                      \
    }                                                                          \
    if (Tt >= 4 && Tt < NROW) {                                                \
        /* ---- PQ(Tt): P band-row Tt-2 (abs gy=gy0+Tt-5) -> dP/eQ[S1] ---- */ \
        float* dp = dP[S1]; float* eq = eQ[S1];                                \
        const int gy = gy0 + Tt - 5;                                           \
        if ((unsigned)gy < (unsigned)H) {                                      \
            const float* xt = xw[S0];  /* ux row Tt-3 */                       \
            const float* xm = xw[S1];  /* ux row Tt-2 */                       \
            const float* xb = xw[S2];  /* ux row Tt-1 */                       \
            const float* yt = yw[S0];                                          \
            const float* ym = yw[S1];                                          \
            const float* yb = yw[S2];                                          \
            float P[6], Q[6];                                                  \
            _Pragma("unroll") for (int c = 0; c < 6; ++c) {                    \
                const float xc = xm[c+1], yc = ym[c+1];                        \
                const float uxx = (xt[c+2]-xt[c]) + 2.f*(xm[c+2]-xm[c])        \
                                + (xb[c+2]-xb[c]);                             \
                const float uxy = (xb[c] + 2.f*xb[c+1] + xb[c+2])              \
                                - (xt[c] + 2.f*xt[c+1] + xt[c+2]);             \
                const float uyy = (yb[c] + 2.f*yb[c+1] + yb[c+2])              \
                                - (yt[c] + 2.f*yt[c+1] + yt[c+2]);             \
                const float den = 1.f + xc*xc + yc*yc;                         \
                const float Gv = (uxx*uyy - uxy*uxy)                           \
                               * __builtin_amdgcn_rcpf(den*den + 1e-6f);       \
                const float phi = __expf(-fabsf(Gv));                          \
                /* xc,yc already 0 at invalid cols; phi finite -> P,Q = 0 */   \
                P[c] = phi * xc;                                               \
                Q[c] = phi * yc;                                               \
            }                                                                  \
            dp[0] = P[2]-P[0]; dp[1] = P[3]-P[1];                              \
            dp[2] = P[4]-P[2]; dp[3] = P[5]-P[3];                              \
            eq[0] = Q[0]+2.f*Q[1]+Q[2]; eq[1] = Q[1]+2.f*Q[2]+Q[3];            \
            eq[2] = Q[2]+2.f*Q[3]+Q[4]; eq[3] = Q[3]+2.f*Q[4]+Q[5];            \
        } else {                                                               \
            _Pragma("unroll") for (int c = 0; c < 4; ++c) { dp[c]=0.f; eq[c]=0.f; } \
        }                                                                      \
    }                                                                          \
    if (Tt >= 6 && Tt < NROW) {                                                \
        /* ---- OUT(Tt): out band-row Tt-3, abs gy = gy0+Tt-6 (in-domain) ---- */ \
        /* P rows: gy-1 -> S2 (w1), gy -> S0 (w2), gy+1 -> S1 (w1) */          \
        f4v o;                                                                 \
        o.x = ur0 + (dP[S2][0] + 2.f*dP[S0][0] + dP[S1][0])                    \
                  + (eQ[S1][0] - eQ[S2][0]);                                   \
        o.y = ur1 + (dP[S2][1] + 2.f*dP[S0][1] + dP[S1][1])                    \
                  + (eQ[S1][1] - eQ[S2][1]);                                   \
        o.z = ur2 + (dP[S2][2] + 2.f*dP[S0][2] + dP[S1][2])                    \
                  + (eQ[S1][2] - eQ[S2][2]);                                   \
        o.w = ur3 + (dP[S2][3] + 2.f*dP[S0][3] + dP[S1][3])                    \
                  + (eQ[S1][3] - eQ[S2][3]);                                   \
        __builtin_nontemporal_store(o, (f4v*)(oc + (long)(gy0 + Tt - 6) * W + c0)); \
    }                                                                          \
} while (0)

__global__ __launch_bounds__(NT) void gcdd_sweep(
    const float* __restrict__ u, float* __restrict__ out, int H, int W)
{
    const int tid   = threadIdx.x;
    const int strip = tid & 127;          // 128 strips x 4 cols = W = 512
    const int band  = tid >> 7;           // 2 bands per block (wave-uniform)
    const int c0    = strip * 4;
    const int gy0   = (blockIdx.y * 2 + band) * HB;
    const long chan = blockIdx.z;
    const float* __restrict__ uc = u + chan * (long)H * W;
    float* __restrict__ oc = out + chan * (long)H * W;

    // Clamped load-base cols (keeps addresses in-bounds; clamped-in values are
    // masked to zero below, implementing the zero-padding of the first conv).
    const int ca = (c0 - 4 < 0) ? 0 : (c0 - 4);
    const int cc = (c0 + 4 > W - 4) ? (W - 4) : (c0 + 4);

    // pend[i] holds u col c0-4+i; validity masks (only edge strips have false).
    bool mU[12];
    #pragma unroll
    for (int i = 0; i < 12; ++i)
        mU[i] = (unsigned)(c0 - 4 + i) < (unsigned)W;
    const bool inb0 = mU[0], inb1 = mU[1], inb2 = mU[2], inb3 = mU[3];
    const bool inb8 = mU[8], inb9 = mU[9], inb10 = mU[10], inb11 = mU[11];

    float pend[12];
    float Du[3][8], Su[3][8];
    float ucen[3][4] = {};
    float xw[3][8], yw[3][8];
    float dP[3][4], eQ[3][4];

    // ---- Prologue: load band-row 0 (abs gy = gy0-3) into pend ----
    {
        const int gy = gy0 - 3;
        if ((unsigned)gy < (unsigned)H) {
            const float* row = uc + (long)gy * W;
            const float4 va = *(const float4*)(row + ca);
            const float4 vb = *(const float4*)(row + c0);
            const float4 vc = *(const float4*)(row + cc);
            pend[0] = inb0  ? va.x : 0.f;  pend[1]  = inb1  ? va.y : 0.f;
            pend[2] = inb2  ? va.z : 0.f;  pend[3]  = inb3  ? va.w : 0.f;
            pend[4] = vb.x;                pend[5]  = vb.y;
            pend[6] = vb.z;                pend[7]  = vb.w;
            pend[8] = inb8  ? vc.x : 0.f;  pend[9]  = inb9  ? vc.y : 0.f;
            pend[10] = inb10 ? vc.z : 0.f; pend[11] = inb11 ? vc.w : 0.f;
        } else {
            #pragma unroll
            for (int i = 0; i < 12; ++i) pend[i] = 0.f;
        }
    }

    // 24 iterations (22 active), 3x-unrolled: all slot indices literal.
    for (int t = 0; t < NROW + 2; t += 3) {
        STEP(t + 0, 0, 1, 2);
        STEP(t + 1, 1, 2, 0);
        STEP(t + 2, 2, 0, 1);
    }
}

extern "C" void kernel_launch(void* const* d_in, const int* in_sizes, int n_in,
                              void* d_out, int out_size, void* d_ws, size_t ws_size,
                              hipStream_t stream) {
    const float* u = (const float*)d_in[0];
    float* out = (float*)d_out;

    const int H = 512, W = 512;
    const int channels = in_sizes[0] / (H * W);  // B*C = 48

    dim3 grid(1, H / (2 * HB), channels);        // 1 x 16 x 48 = 768 blocks
    dim3 block(NT);
    gcdd_sweep<<<grid, block, 0, stream>>>(u, out, H, W);
}